// Round 6
// baseline (883.257 us; speedup 1.0000x reference)
//
#include <hip/hip_runtime.h>

// Problem constants (from reference)
#define NN 100000
#define EE 1600000
#define DD 128   // input dim
#define HH 128   // hidden dim
#define OO 64    // output dim

#define SCAN_BLOCKS 256
#define NPART 4          // dst-range partitions for CSR fill (write locality)
#define MAXDEG 512       // degree-sort bins (degree >= 511 clamps)

typedef unsigned short u16;
typedef __attribute__((ext_vector_type(8))) short bf16x8;  // 8 bf16 = 4 VGPR
typedef __attribute__((ext_vector_type(4))) float f32x4;

// ---------------------------------------------------------------------------
// bf16 helpers (RNE round, finite values only)
__device__ __forceinline__ u16 f2b(float f) {
  union { float f; unsigned u; } v; v.f = f;
  unsigned r = v.u + 0x7fffu + ((v.u >> 16) & 1u);
  return (u16)(r >> 16);
}
__device__ __forceinline__ float b2f(unsigned h) {
  union { unsigned u; float f; } v; v.u = h << 16;
  return v.f;
}
__device__ __forceinline__ void fma8(float* acc, uint4 v, float w) {
  acc[0] = fmaf(b2f(v.x & 0xffffu), w, acc[0]);
  acc[1] = fmaf(b2f(v.x >> 16), w, acc[1]);
  acc[2] = fmaf(b2f(v.y & 0xffffu), w, acc[2]);
  acc[3] = fmaf(b2f(v.y >> 16), w, acc[3]);
  acc[4] = fmaf(b2f(v.z & 0xffffu), w, acc[4]);
  acc[5] = fmaf(b2f(v.z >> 16), w, acc[5]);
  acc[6] = fmaf(b2f(v.w & 0xffffu), w, acc[6]);
  acc[7] = fmaf(b2f(v.w >> 16), w, acc[7]);
}

// ---------------------------------------------------------------------------
// Convert x [N,128] fp32 -> bf16 (8 elems per thread)
__global__ __launch_bounds__(256) void cvt_x_k(const float* __restrict__ x,
                                               u16* __restrict__ xb) {
  int i = blockIdx.x * 256 + threadIdx.x;  // chunk of 8 elems
  if (i >= NN * DD / 8) return;
  const float4* p = reinterpret_cast<const float4*>(x) + (size_t)i * 2;
  float4 a = p[0], b = p[1];
  uint4 o;
  o.x = (unsigned)f2b(a.x) | ((unsigned)f2b(a.y) << 16);
  o.y = (unsigned)f2b(a.z) | ((unsigned)f2b(a.w) << 16);
  o.z = (unsigned)f2b(b.x) | ((unsigned)f2b(b.y) << 16);
  o.w = (unsigned)f2b(b.z) | ((unsigned)f2b(b.w) << 16);
  reinterpret_cast<uint4*>(xb)[i] = o;
}

// ---------------------------------------------------------------------------
// Build stacked, transposed bf16 weights.
__global__ __launch_bounds__(256) void cvt_w_k(
    const float* __restrict__ Wr1, const float* __restrict__ Wo1,
    const float* __restrict__ Wr2, const float* __restrict__ Wo2,
    u16* __restrict__ Wt1, u16* __restrict__ Wt2) {
  int i = blockIdx.x * 256 + threadIdx.x;
  if (i < 128 * 256) {
    int n = i >> 8, k = i & 255;
    float v = (k < 128) ? Wr1[k * 128 + n] : Wo1[(k - 128) * 128 + n];
    Wt1[i] = f2b(v);
  } else if (i < 128 * 256 + 64 * 256) {
    int j = i - 128 * 256;
    int n = j >> 8, k = j & 255;
    float v = (k < 128) ? Wr2[k * 64 + n] : Wo2[(k - 128) * 64 + n];
    Wt2[j] = f2b(v);
  }
}

// ---------------------------------------------------------------------------
// Pass 1: count in-degree per destination node (into cursor[])
__global__ __launch_bounds__(256) void count_k(const int* __restrict__ ei,
                                               int* __restrict__ cnt, int E) {
  int e = blockIdx.x * 256 + threadIdx.x;
  if (e < E) atomicAdd(&cnt[ei[E + e]], 1);
}

// Pass 2a: per-block partial sums of cnt[] chunks.
__global__ __launch_bounds__(256) void scan_partial_k(const int* __restrict__ cnt,
                                                      int* __restrict__ blk_sum, int n) {
  __shared__ int red[256];
  const int chunk = (n + SCAN_BLOCKS - 1) / SCAN_BLOCKS;
  const int beg = blockIdx.x * chunk;
  const int end = min(n, beg + chunk);
  int local = 0;
  for (int i = beg + threadIdx.x; i < end; i += 256) local += cnt[i];
  red[threadIdx.x] = local;
  __syncthreads();
#pragma unroll
  for (int off = 128; off > 0; off >>= 1) {
    if (threadIdx.x < off) red[threadIdx.x] += red[threadIdx.x + off];
    __syncthreads();
  }
  if (threadIdx.x == 0) blk_sum[blockIdx.x] = red[0];
}

// Pass 2b: single-block exclusive scan of SCAN_BLOCKS block sums (in-place).
__global__ __launch_bounds__(SCAN_BLOCKS) void scan_blk_k(int* __restrict__ blk_sum) {
  __shared__ int s[SCAN_BLOCKS];
  const int t = threadIdx.x;
  int v = blk_sum[t];
  s[t] = v;
  __syncthreads();
#pragma unroll
  for (int off = 1; off < SCAN_BLOCKS; off <<= 1) {
    int u = (t >= off) ? s[t - off] : 0;
    __syncthreads();
    s[t] += u;
    __syncthreads();
  }
  blk_sum[t] = s[t] - v;  // exclusive
}

// Pass 2c: per-block exclusive scan of its chunk, seeded by blk_sum.
__global__ __launch_bounds__(256) void scan_final_k(int* __restrict__ cursor,
                                                    int* __restrict__ row_off,
                                                    const int* __restrict__ blk_sum, int n) {
  __shared__ int s[256];
  const int chunk = (n + SCAN_BLOCKS - 1) / SCAN_BLOCKS;
  const int beg = blockIdx.x * chunk;
  const int end = min(n, beg + chunk);
  const int sub = (chunk + 255) / 256;
  const int tbeg = beg + threadIdx.x * sub;
  const int tend = min(end, tbeg + sub);
  int local = 0;
  for (int i = tbeg; i < tend; ++i) local += cursor[i];
  s[threadIdx.x] = local;
  __syncthreads();
#pragma unroll
  for (int off = 1; off < 256; off <<= 1) {
    int u = (threadIdx.x >= off) ? s[threadIdx.x - off] : 0;
    __syncthreads();
    s[threadIdx.x] += u;
    __syncthreads();
  }
  int running = blk_sum[blockIdx.x] + s[threadIdx.x] - local;
  for (int i = tbeg; i < tend; ++i) {
    int d = cursor[i];
    row_off[i] = running;
    cursor[i] = running;
    running += d;
  }
}

// ---------------------------------------------------------------------------
// Pass 3 (partitioned): fill CSR records for dst in [lo, hi), fusing sigmoid.
__global__ __launch_bounds__(256) void fill_part_k(const int* __restrict__ ei,
                                                   const float* __restrict__ w,
                                                   int* __restrict__ cursor,
                                                   uint2* __restrict__ recs,
                                                   int lo, int hi, int E) {
  int e = blockIdx.x * 256 + threadIdx.x;
  if (e >= E) return;
  int dst = ei[E + e];
  if (dst < lo || dst >= hi) return;
  int pos = atomicAdd(&cursor[dst], 1);
  float sig = 1.0f / (1.0f + expf(-w[e]));
  recs[pos] = make_uint2((unsigned)ei[e], __float_as_uint(sig));
}

// ---------------------------------------------------------------------------
// Degree counting sort: hist -> exclusive scan -> scatter perm.
__global__ __launch_bounds__(256) void dhist_k(const int* __restrict__ row_off,
                                               const int* __restrict__ row_end,
                                               int* __restrict__ dhist) {
  int n = blockIdx.x * 256 + threadIdx.x;
  if (n >= NN) return;
  int d = min(row_end[n] - row_off[n], MAXDEG - 1);
  atomicAdd(&dhist[d], 1);
}

__global__ __launch_bounds__(MAXDEG) void dscan_k(int* __restrict__ dhist) {
  __shared__ int s[MAXDEG];
  const int t = threadIdx.x;
  int v = dhist[t];
  s[t] = v;
  __syncthreads();
#pragma unroll
  for (int off = 1; off < MAXDEG; off <<= 1) {
    int u = (t >= off) ? s[t - off] : 0;
    __syncthreads();
    s[t] += u;
    __syncthreads();
  }
  dhist[t] = s[t] - v;  // exclusive (becomes bin cursor)
}

__global__ __launch_bounds__(256) void dperm_k(const int* __restrict__ row_off,
                                               const int* __restrict__ row_end,
                                               int* __restrict__ dcur,
                                               int* __restrict__ perm) {
  int n = blockIdx.x * 256 + threadIdx.x;
  if (n >= NN) return;
  int d = min(row_end[n] - row_off[n], MAXDEG - 1);
  int pos = atomicAdd(&dcur[d], 1);
  perm[pos] = n;
}

// ---------------------------------------------------------------------------
// Aggregation as gather over bf16 features: 16 lanes per node, 8 bf16 each.
// Nodes processed in degree-sorted order (perm) so the 4 groups within a wave
// have near-equal trip counts. Edge loop unrolled x4 for memory-level parallelism.
__global__ __launch_bounds__(256) void gather_k(
    const u16* __restrict__ feat, const int* __restrict__ row_off,
    const int* __restrict__ row_end, const uint2* __restrict__ recs,
    const int* __restrict__ perm, u16* __restrict__ aggr) {
  int gid = blockIdx.x * 256 + threadIdx.x;
  int g = gid >> 4;
  int c = gid & 15;  // 8-elem chunk
  if (g >= NN) return;
  int node = perm[g];
  int beg = row_off[node];
  int end = row_end[node];
  float acc[8] = {0.f, 0.f, 0.f, 0.f, 0.f, 0.f, 0.f, 0.f};
  int e = beg;
  for (; e + 4 <= end; e += 4) {
    uint2 r0 = recs[e + 0];
    uint2 r1 = recs[e + 1];
    uint2 r2 = recs[e + 2];
    uint2 r3 = recs[e + 3];
    uint4 v0 = *reinterpret_cast<const uint4*>(feat + (size_t)r0.x * DD + c * 8);
    uint4 v1 = *reinterpret_cast<const uint4*>(feat + (size_t)r1.x * DD + c * 8);
    uint4 v2 = *reinterpret_cast<const uint4*>(feat + (size_t)r2.x * DD + c * 8);
    uint4 v3 = *reinterpret_cast<const uint4*>(feat + (size_t)r3.x * DD + c * 8);
    fma8(acc, v0, __uint_as_float(r0.y));
    fma8(acc, v1, __uint_as_float(r1.y));
    fma8(acc, v2, __uint_as_float(r2.y));
    fma8(acc, v3, __uint_as_float(r3.y));
  }
  for (; e < end; ++e) {
    uint2 r = recs[e];
    uint4 v = *reinterpret_cast<const uint4*>(feat + (size_t)r.x * DD + c * 8);
    fma8(acc, v, __uint_as_float(r.y));
  }
  uint4 o;
  o.x = (unsigned)f2b(acc[0]) | ((unsigned)f2b(acc[1]) << 16);
  o.y = (unsigned)f2b(acc[2]) | ((unsigned)f2b(acc[3]) << 16);
  o.z = (unsigned)f2b(acc[4]) | ((unsigned)f2b(acc[5]) << 16);
  o.w = (unsigned)f2b(acc[6]) | ((unsigned)f2b(acc[7]) << 16);
  *reinterpret_cast<uint4*>(aggr + (size_t)node * DD + c * 8) = o;
}

// ---------------------------------------------------------------------------
// MFMA dual-GEMM:  C = (relu?)( [A1 | A2] @ Bt^T + bias )
template <int HO, bool RELU, bool OUTBF16>
__global__ __launch_bounds__(256) void gemm_mfma_k(
    const u16* __restrict__ A1, const u16* __restrict__ A2,
    const u16* __restrict__ Bt, const float* __restrict__ bias,
    void* __restrict__ Cout, int n_rows) {
  constexpr int CG = HO / 16;
  __shared__ u16 As[64][40];
  __shared__ u16 Bs[HO][40];

  const int t = threadIdx.x;
  const int w = t >> 6;
  const int lane = t & 63;
  const int row0 = blockIdx.x * 64;

  f32x4 acc[CG];
#pragma unroll
  for (int cg = 0; cg < CG; ++cg) acc[cg] = (f32x4){0.f, 0.f, 0.f, 0.f};

  const int arow = w * 16 + (lane & 15);
  const int kq = (lane >> 4) * 8;

  for (int k0 = 0; k0 < 256; k0 += 32) {
    {
      int node = t >> 2;
      int koff = (t & 3) * 8;
      int k = k0 + koff;
      int gr = row0 + node;
      uint4 v = make_uint4(0u, 0u, 0u, 0u);
      if (gr < n_rows) {
        const u16* src = (k < 128) ? (A1 + (size_t)gr * 128 + k)
                                   : (A2 + (size_t)gr * 128 + (k - 128));
        v = *reinterpret_cast<const uint4*>(src);
      }
      *reinterpret_cast<uint4*>(&As[node][koff]) = v;
    }
#pragma unroll
    for (int i = 0; i < CG / 4; ++i) {
      int c2 = t + i * 256;
      int n = c2 >> 2;
      int koff = (c2 & 3) * 8;
      uint4 v = *reinterpret_cast<const uint4*>(Bt + (size_t)n * 256 + k0 + koff);
      *reinterpret_cast<uint4*>(&Bs[n][koff]) = v;
    }
    __syncthreads();

    bf16x8 a = *reinterpret_cast<const bf16x8*>(&As[arow][kq]);
#pragma unroll
    for (int cg = 0; cg < CG; ++cg) {
      bf16x8 b = *reinterpret_cast<const bf16x8*>(&Bs[cg * 16 + (lane & 15)][kq]);
      acc[cg] = __builtin_amdgcn_mfma_f32_16x16x32_bf16(a, b, acc[cg], 0, 0, 0);
    }
    __syncthreads();
  }

  const int rbase = w * 16 + ((lane >> 4) << 2);
#pragma unroll
  for (int cg = 0; cg < CG; ++cg) {
    int col = cg * 16 + (lane & 15);
    float bia = bias[col];
#pragma unroll
    for (int j = 0; j < 4; ++j) {
      int gr = row0 + rbase + j;
      if (gr < n_rows) {
        float v = acc[cg][j] + bia;
        if (RELU) v = fmaxf(v, 0.f);
        if (OUTBF16) ((u16*)Cout)[(size_t)gr * HO + col] = f2b(v);
        else ((float*)Cout)[(size_t)gr * HO + col] = v;
      }
    }
  }
}

// ---------------------------------------------------------------------------
extern "C" void kernel_launch(void* const* d_in, const int* in_sizes, int n_in,
                              void* d_out, int out_size, void* d_ws, size_t ws_size,
                              hipStream_t stream) {
  const float* x   = (const float*)d_in[0];
  const float* w   = (const float*)d_in[1];
  const int*   ei  = (const int*)d_in[2];   // [2, E]: row0=src, row1=dst
  const float* Wr1 = (const float*)d_in[3];
  const float* br1 = (const float*)d_in[4];
  const float* Wo1 = (const float*)d_in[5];
  const float* Wr2 = (const float*)d_in[6];
  const float* br2 = (const float*)d_in[7];
  const float* Wo2 = (const float*)d_in[8];
  float* out = (float*)d_out;

  // Workspace layout (bytes, all offsets 16B-aligned):
  char* ws = (char*)d_ws;
  int*   row_off = (int*)(ws);                        // N ints        400,000
  int*   cursor  = (int*)(ws + 400000);               // N ints        400,000
  int*   blk_sum = (int*)(ws + 800000);               // 256 ints        1,024
  uint2* recs    = (uint2*)(ws + 801024);             // E uint2    12,800,000
  u16*   xb      = (u16*)(ws + 13601024);             // N*128 bf16 25,600,000
  u16*   hb      = (u16*)(ws + 39201024);             // N*128 bf16 25,600,000
  u16*   aggrb   = (u16*)(ws + 64801024);             // N*128 bf16 25,600,000
  u16*   Wt1     = (u16*)(ws + 90401024);             // 128*256 bf16   65,536
  u16*   Wt2     = (u16*)(ws + 90466560);             // 64*256 bf16    32,768
  int*   dhist   = (int*)(ws + 90499328);             // 512 ints        2,048
  int*   perm    = (int*)(ws + 90501376);             // N ints        400,000
  // total ~90.9 MB

  const int egrid = (EE + 255) / 256;
  const int ngrid = (NN + 255) / 256;

  // ---- Prep: bf16 conversions ----
  cvt_x_k<<<NN * DD / 8 / 256, 256, 0, stream>>>(x, xb);
  cvt_w_k<<<(192 * 256 + 255) / 256, 256, 0, stream>>>(Wr1, Wo1, Wr2, Wo2, Wt1, Wt2);

  // ---- Build CSR (grouped by dst), fused sigmoid ----
  hipMemsetAsync(cursor, 0, (size_t)NN * sizeof(int), stream);
  count_k<<<egrid, 256, 0, stream>>>(ei, cursor, EE);
  scan_partial_k<<<SCAN_BLOCKS, 256, 0, stream>>>(cursor, blk_sum, NN);
  scan_blk_k<<<1, SCAN_BLOCKS, 0, stream>>>(blk_sum);
  scan_final_k<<<SCAN_BLOCKS, 256, 0, stream>>>(cursor, row_off, blk_sum, NN);
  {
    const int pstep = (NN + NPART - 1) / NPART;
    for (int p = 0; p < NPART; ++p) {
      int lo = p * pstep;
      int hi = min(NN, lo + pstep);
      fill_part_k<<<egrid, 256, 0, stream>>>(ei, w, cursor, recs, lo, hi, EE);
    }
  }
  // after fill: cursor[n] == row_off[n+1]  (row end)

  // ---- Degree-sorted node permutation (counting sort) ----
  hipMemsetAsync(dhist, 0, MAXDEG * sizeof(int), stream);
  dhist_k<<<ngrid, 256, 0, stream>>>(row_off, cursor, dhist);
  dscan_k<<<1, MAXDEG, 0, stream>>>(dhist);
  dperm_k<<<ngrid, 256, 0, stream>>>(row_off, cursor, dhist, perm);

  const int ggrid = (NN * 16 + 255) / 256;
  const int mgrid = (NN + 63) / 64;

  // ---- Layer 1 ----
  gather_k<<<ggrid, 256, 0, stream>>>(xb, row_off, cursor, recs, perm, aggrb);
  gemm_mfma_k<HH, true, true><<<mgrid, 256, 0, stream>>>(aggrb, xb, Wt1, br1, hb, NN);

  // ---- Layer 2 ----
  gather_k<<<ggrid, 256, 0, stream>>>(hb, row_off, cursor, recs, perm, aggrb);
  gemm_mfma_k<OO, false, false><<<mgrid, 256, 0, stream>>>(aggrb, hb, Wt2, br2, out, NN);
}

// Round 7
// 371.802 us; speedup vs baseline: 2.3756x; 2.3756x over previous
//
#include <hip/hip_runtime.h>

// Problem constants (from reference)
#define NN 100000
#define EE 1600000
#define DD 128   // input dim
#define HH 128   // hidden dim
#define OO 64    // output dim

#define SCAN_BLOCKS 256
#define NPART 4          // dst-range partitions for CSR fill (write locality)
#define MAXDEG 512       // degree-sort bins (degree >= 511 clamps)

typedef unsigned short u16;
typedef __attribute__((ext_vector_type(8))) short bf16x8;  // 8 bf16 = 4 VGPR
typedef __attribute__((ext_vector_type(4))) float f32x4;

// ---------------------------------------------------------------------------
// bf16 helpers (RNE round, finite values only)
__device__ __forceinline__ u16 f2b(float f) {
  union { float f; unsigned u; } v; v.f = f;
  unsigned r = v.u + 0x7fffu + ((v.u >> 16) & 1u);
  return (u16)(r >> 16);
}
__device__ __forceinline__ float b2f(unsigned h) {
  union { unsigned u; float f; } v; v.u = h << 16;
  return v.f;
}
__device__ __forceinline__ void fma8(float* acc, uint4 v, float w) {
  acc[0] = fmaf(b2f(v.x & 0xffffu), w, acc[0]);
  acc[1] = fmaf(b2f(v.x >> 16), w, acc[1]);
  acc[2] = fmaf(b2f(v.y & 0xffffu), w, acc[2]);
  acc[3] = fmaf(b2f(v.y >> 16), w, acc[3]);
  acc[4] = fmaf(b2f(v.z & 0xffffu), w, acc[4]);
  acc[5] = fmaf(b2f(v.z >> 16), w, acc[5]);
  acc[6] = fmaf(b2f(v.w & 0xffffu), w, acc[6]);
  acc[7] = fmaf(b2f(v.w >> 16), w, acc[7]);
}

// ---------------------------------------------------------------------------
// Convert x [N,128] fp32 -> bf16 (8 elems per thread)
__global__ __launch_bounds__(256) void cvt_x_k(const float* __restrict__ x,
                                               u16* __restrict__ xb) {
  int i = blockIdx.x * 256 + threadIdx.x;  // chunk of 8 elems
  if (i >= NN * DD / 8) return;
  const float4* p = reinterpret_cast<const float4*>(x) + (size_t)i * 2;
  float4 a = p[0], b = p[1];
  uint4 o;
  o.x = (unsigned)f2b(a.x) | ((unsigned)f2b(a.y) << 16);
  o.y = (unsigned)f2b(a.z) | ((unsigned)f2b(a.w) << 16);
  o.z = (unsigned)f2b(b.x) | ((unsigned)f2b(b.y) << 16);
  o.w = (unsigned)f2b(b.z) | ((unsigned)f2b(b.w) << 16);
  reinterpret_cast<uint4*>(xb)[i] = o;
}

// ---------------------------------------------------------------------------
// Build stacked, transposed bf16 weights.
__global__ __launch_bounds__(256) void cvt_w_k(
    const float* __restrict__ Wr1, const float* __restrict__ Wo1,
    const float* __restrict__ Wr2, const float* __restrict__ Wo2,
    u16* __restrict__ Wt1, u16* __restrict__ Wt2) {
  int i = blockIdx.x * 256 + threadIdx.x;
  if (i < 128 * 256) {
    int n = i >> 8, k = i & 255;
    float v = (k < 128) ? Wr1[k * 128 + n] : Wo1[(k - 128) * 128 + n];
    Wt1[i] = f2b(v);
  } else if (i < 128 * 256 + 64 * 256) {
    int j = i - 128 * 256;
    int n = j >> 8, k = j & 255;
    float v = (k < 128) ? Wr2[k * 64 + n] : Wo2[(k - 128) * 64 + n];
    Wt2[j] = f2b(v);
  }
}

// ---------------------------------------------------------------------------
// Pass 1: count in-degree per destination node (into cursor[])
__global__ __launch_bounds__(256) void count_k(const int* __restrict__ ei,
                                               int* __restrict__ cnt, int E) {
  int e = blockIdx.x * 256 + threadIdx.x;
  if (e < E) atomicAdd(&cnt[ei[E + e]], 1);
}

// Pass 2a: per-block partial sums of cnt[] chunks.
__global__ __launch_bounds__(256) void scan_partial_k(const int* __restrict__ cnt,
                                                      int* __restrict__ blk_sum, int n) {
  __shared__ int red[256];
  const int chunk = (n + SCAN_BLOCKS - 1) / SCAN_BLOCKS;
  const int beg = blockIdx.x * chunk;
  const int end = min(n, beg + chunk);
  int local = 0;
  for (int i = beg + threadIdx.x; i < end; i += 256) local += cnt[i];
  red[threadIdx.x] = local;
  __syncthreads();
#pragma unroll
  for (int off = 128; off > 0; off >>= 1) {
    if (threadIdx.x < off) red[threadIdx.x] += red[threadIdx.x + off];
    __syncthreads();
  }
  if (threadIdx.x == 0) blk_sum[blockIdx.x] = red[0];
}

// Pass 2b: single-block exclusive scan of SCAN_BLOCKS block sums (in-place).
__global__ __launch_bounds__(SCAN_BLOCKS) void scan_blk_k(int* __restrict__ blk_sum) {
  __shared__ int s[SCAN_BLOCKS];
  const int t = threadIdx.x;
  int v = blk_sum[t];
  s[t] = v;
  __syncthreads();
#pragma unroll
  for (int off = 1; off < SCAN_BLOCKS; off <<= 1) {
    int u = (t >= off) ? s[t - off] : 0;
    __syncthreads();
    s[t] += u;
    __syncthreads();
  }
  blk_sum[t] = s[t] - v;  // exclusive
}

// Pass 2c: per-block exclusive scan of its chunk, seeded by blk_sum.
__global__ __launch_bounds__(256) void scan_final_k(int* __restrict__ cursor,
                                                    int* __restrict__ row_off,
                                                    const int* __restrict__ blk_sum, int n) {
  __shared__ int s[256];
  const int chunk = (n + SCAN_BLOCKS - 1) / SCAN_BLOCKS;
  const int beg = blockIdx.x * chunk;
  const int end = min(n, beg + chunk);
  const int sub = (chunk + 255) / 256;
  const int tbeg = beg + threadIdx.x * sub;
  const int tend = min(end, tbeg + sub);
  int local = 0;
  for (int i = tbeg; i < tend; ++i) local += cursor[i];
  s[threadIdx.x] = local;
  __syncthreads();
#pragma unroll
  for (int off = 1; off < 256; off <<= 1) {
    int u = (threadIdx.x >= off) ? s[threadIdx.x - off] : 0;
    __syncthreads();
    s[threadIdx.x] += u;
    __syncthreads();
  }
  int running = blk_sum[blockIdx.x] + s[threadIdx.x] - local;
  for (int i = tbeg; i < tend; ++i) {
    int d = cursor[i];
    row_off[i] = running;
    cursor[i] = running;
    running += d;
  }
}

// ---------------------------------------------------------------------------
// Pass 3 (partitioned): fill CSR records for dst in [lo, hi), fusing sigmoid.
__global__ __launch_bounds__(256) void fill_part_k(const int* __restrict__ ei,
                                                   const float* __restrict__ w,
                                                   int* __restrict__ cursor,
                                                   uint2* __restrict__ recs,
                                                   int lo, int hi, int E) {
  int e = blockIdx.x * 256 + threadIdx.x;
  if (e >= E) return;
  int dst = ei[E + e];
  if (dst < lo || dst >= hi) return;
  int pos = atomicAdd(&cursor[dst], 1);
  float sig = 1.0f / (1.0f + expf(-w[e]));
  recs[pos] = make_uint2((unsigned)ei[e], __float_as_uint(sig));
}

// ---------------------------------------------------------------------------
// Degree counting sort with LDS pre-aggregation (G12: no hot global atomics).
// dhist: per-block LDS histogram, then one global atomicAdd per nonzero bin.
__global__ __launch_bounds__(256) void dhist_k(const int* __restrict__ row_off,
                                               const int* __restrict__ row_end,
                                               int* __restrict__ dhist) {
  __shared__ int lh[MAXDEG];
  for (int i = threadIdx.x; i < MAXDEG; i += 256) lh[i] = 0;
  __syncthreads();
  int n = blockIdx.x * 256 + threadIdx.x;
  if (n < NN) {
    int d = min(row_end[n] - row_off[n], MAXDEG - 1);
    atomicAdd(&lh[d], 1);
  }
  __syncthreads();
  for (int i = threadIdx.x; i < MAXDEG; i += 256) {
    int c = lh[i];
    if (c) atomicAdd(&dhist[i], c);
  }
}

__global__ __launch_bounds__(MAXDEG) void dscan_k(int* __restrict__ dhist) {
  __shared__ int s[MAXDEG];
  const int t = threadIdx.x;
  int v = dhist[t];
  s[t] = v;
  __syncthreads();
#pragma unroll
  for (int off = 1; off < MAXDEG; off <<= 1) {
    int u = (t >= off) ? s[t - off] : 0;
    __syncthreads();
    s[t] += u;
    __syncthreads();
  }
  dhist[t] = s[t] - v;  // exclusive (becomes bin cursor)
}

// dperm: LDS histogram gives each thread a local rank; one global atomicAdd
// per (block, nonzero bin) reserves a contiguous range; threads write there.
__global__ __launch_bounds__(256) void dperm_k(const int* __restrict__ row_off,
                                               const int* __restrict__ row_end,
                                               int* __restrict__ dcur,
                                               int* __restrict__ perm) {
  __shared__ int lh[MAXDEG];
  __shared__ int lbase[MAXDEG];
  for (int i = threadIdx.x; i < MAXDEG; i += 256) lh[i] = 0;
  __syncthreads();
  int n = blockIdx.x * 256 + threadIdx.x;
  int d = 0, lpos = 0;
  if (n < NN) {
    d = min(row_end[n] - row_off[n], MAXDEG - 1);
    lpos = atomicAdd(&lh[d], 1);
  }
  __syncthreads();
  for (int i = threadIdx.x; i < MAXDEG; i += 256) {
    int c = lh[i];
    if (c) lbase[i] = atomicAdd(&dcur[i], c);
  }
  __syncthreads();
  if (n < NN) perm[lbase[d] + lpos] = n;
}

// ---------------------------------------------------------------------------
// Aggregation as gather over bf16 features: 16 lanes per node, 8 bf16 each.
// Nodes processed in degree-sorted order (perm); edge loop unrolled x4.
__global__ __launch_bounds__(256) void gather_k(
    const u16* __restrict__ feat, const int* __restrict__ row_off,
    const int* __restrict__ row_end, const uint2* __restrict__ recs,
    const int* __restrict__ perm, u16* __restrict__ aggr) {
  int gid = blockIdx.x * 256 + threadIdx.x;
  int g = gid >> 4;
  int c = gid & 15;  // 8-elem chunk
  if (g >= NN) return;
  int node = perm[g];
  int beg = row_off[node];
  int end = row_end[node];
  float acc[8] = {0.f, 0.f, 0.f, 0.f, 0.f, 0.f, 0.f, 0.f};
  int e = beg;
  for (; e + 4 <= end; e += 4) {
    uint2 r0 = recs[e + 0];
    uint2 r1 = recs[e + 1];
    uint2 r2 = recs[e + 2];
    uint2 r3 = recs[e + 3];
    uint4 v0 = *reinterpret_cast<const uint4*>(feat + (size_t)r0.x * DD + c * 8);
    uint4 v1 = *reinterpret_cast<const uint4*>(feat + (size_t)r1.x * DD + c * 8);
    uint4 v2 = *reinterpret_cast<const uint4*>(feat + (size_t)r2.x * DD + c * 8);
    uint4 v3 = *reinterpret_cast<const uint4*>(feat + (size_t)r3.x * DD + c * 8);
    fma8(acc, v0, __uint_as_float(r0.y));
    fma8(acc, v1, __uint_as_float(r1.y));
    fma8(acc, v2, __uint_as_float(r2.y));
    fma8(acc, v3, __uint_as_float(r3.y));
  }
  for (; e < end; ++e) {
    uint2 r = recs[e];
    uint4 v = *reinterpret_cast<const uint4*>(feat + (size_t)r.x * DD + c * 8);
    fma8(acc, v, __uint_as_float(r.y));
  }
  uint4 o;
  o.x = (unsigned)f2b(acc[0]) | ((unsigned)f2b(acc[1]) << 16);
  o.y = (unsigned)f2b(acc[2]) | ((unsigned)f2b(acc[3]) << 16);
  o.z = (unsigned)f2b(acc[4]) | ((unsigned)f2b(acc[5]) << 16);
  o.w = (unsigned)f2b(acc[6]) | ((unsigned)f2b(acc[7]) << 16);
  *reinterpret_cast<uint4*>(aggr + (size_t)node * DD + c * 8) = o;
}

// ---------------------------------------------------------------------------
// MFMA dual-GEMM:  C = (relu?)( [A1 | A2] @ Bt^T + bias )
template <int HO, bool RELU, bool OUTBF16>
__global__ __launch_bounds__(256) void gemm_mfma_k(
    const u16* __restrict__ A1, const u16* __restrict__ A2,
    const u16* __restrict__ Bt, const float* __restrict__ bias,
    void* __restrict__ Cout, int n_rows) {
  constexpr int CG = HO / 16;
  __shared__ u16 As[64][40];
  __shared__ u16 Bs[HO][40];

  const int t = threadIdx.x;
  const int w = t >> 6;
  const int lane = t & 63;
  const int row0 = blockIdx.x * 64;

  f32x4 acc[CG];
#pragma unroll
  for (int cg = 0; cg < CG; ++cg) acc[cg] = (f32x4){0.f, 0.f, 0.f, 0.f};

  const int arow = w * 16 + (lane & 15);
  const int kq = (lane >> 4) * 8;

  for (int k0 = 0; k0 < 256; k0 += 32) {
    {
      int node = t >> 2;
      int koff = (t & 3) * 8;
      int k = k0 + koff;
      int gr = row0 + node;
      uint4 v = make_uint4(0u, 0u, 0u, 0u);
      if (gr < n_rows) {
        const u16* src = (k < 128) ? (A1 + (size_t)gr * 128 + k)
                                   : (A2 + (size_t)gr * 128 + (k - 128));
        v = *reinterpret_cast<const uint4*>(src);
      }
      *reinterpret_cast<uint4*>(&As[node][koff]) = v;
    }
#pragma unroll
    for (int i = 0; i < CG / 4; ++i) {
      int c2 = t + i * 256;
      int n = c2 >> 2;
      int koff = (c2 & 3) * 8;
      uint4 v = *reinterpret_cast<const uint4*>(Bt + (size_t)n * 256 + k0 + koff);
      *reinterpret_cast<uint4*>(&Bs[n][koff]) = v;
    }
    __syncthreads();

    bf16x8 a = *reinterpret_cast<const bf16x8*>(&As[arow][kq]);
#pragma unroll
    for (int cg = 0; cg < CG; ++cg) {
      bf16x8 b = *reinterpret_cast<const bf16x8*>(&Bs[cg * 16 + (lane & 15)][kq]);
      acc[cg] = __builtin_amdgcn_mfma_f32_16x16x32_bf16(a, b, acc[cg], 0, 0, 0);
    }
    __syncthreads();
  }

  const int rbase = w * 16 + ((lane >> 4) << 2);
#pragma unroll
  for (int cg = 0; cg < CG; ++cg) {
    int col = cg * 16 + (lane & 15);
    float bia = bias[col];
#pragma unroll
    for (int j = 0; j < 4; ++j) {
      int gr = row0 + rbase + j;
      if (gr < n_rows) {
        float v = acc[cg][j] + bia;
        if (RELU) v = fmaxf(v, 0.f);
        if (OUTBF16) ((u16*)Cout)[(size_t)gr * HO + col] = f2b(v);
        else ((float*)Cout)[(size_t)gr * HO + col] = v;
      }
    }
  }
}

// ---------------------------------------------------------------------------
extern "C" void kernel_launch(void* const* d_in, const int* in_sizes, int n_in,
                              void* d_out, int out_size, void* d_ws, size_t ws_size,
                              hipStream_t stream) {
  const float* x   = (const float*)d_in[0];
  const float* w   = (const float*)d_in[1];
  const int*   ei  = (const int*)d_in[2];   // [2, E]: row0=src, row1=dst
  const float* Wr1 = (const float*)d_in[3];
  const float* br1 = (const float*)d_in[4];
  const float* Wo1 = (const float*)d_in[5];
  const float* Wr2 = (const float*)d_in[6];
  const float* br2 = (const float*)d_in[7];
  const float* Wo2 = (const float*)d_in[8];
  float* out = (float*)d_out;

  // Workspace layout (bytes, all offsets 16B-aligned):
  char* ws = (char*)d_ws;
  int*   row_off = (int*)(ws);                        // N ints        400,000
  int*   cursor  = (int*)(ws + 400000);               // N ints        400,000
  int*   blk_sum = (int*)(ws + 800000);               // 256 ints        1,024
  uint2* recs    = (uint2*)(ws + 801024);             // E uint2    12,800,000
  u16*   xb      = (u16*)(ws + 13601024);             // N*128 bf16 25,600,000
  u16*   hb      = (u16*)(ws + 39201024);             // N*128 bf16 25,600,000
  u16*   aggrb   = (u16*)(ws + 64801024);             // N*128 bf16 25,600,000
  u16*   Wt1     = (u16*)(ws + 90401024);             // 128*256 bf16   65,536
  u16*   Wt2     = (u16*)(ws + 90466560);             // 64*256 bf16    32,768
  int*   dhist   = (int*)(ws + 90499328);             // 512 ints        2,048
  int*   perm    = (int*)(ws + 90501376);             // N ints        400,000
  // total ~90.9 MB

  const int egrid = (EE + 255) / 256;
  const int ngrid = (NN + 255) / 256;

  // ---- Prep: bf16 conversions ----
  cvt_x_k<<<NN * DD / 8 / 256, 256, 0, stream>>>(x, xb);
  cvt_w_k<<<(192 * 256 + 255) / 256, 256, 0, stream>>>(Wr1, Wo1, Wr2, Wo2, Wt1, Wt2);

  // ---- Build CSR (grouped by dst), fused sigmoid ----
  hipMemsetAsync(cursor, 0, (size_t)NN * sizeof(int), stream);
  count_k<<<egrid, 256, 0, stream>>>(ei, cursor, EE);
  scan_partial_k<<<SCAN_BLOCKS, 256, 0, stream>>>(cursor, blk_sum, NN);
  scan_blk_k<<<1, SCAN_BLOCKS, 0, stream>>>(blk_sum);
  scan_final_k<<<SCAN_BLOCKS, 256, 0, stream>>>(cursor, row_off, blk_sum, NN);
  {
    const int pstep = (NN + NPART - 1) / NPART;
    for (int p = 0; p < NPART; ++p) {
      int lo = p * pstep;
      int hi = min(NN, lo + pstep);
      fill_part_k<<<egrid, 256, 0, stream>>>(ei, w, cursor, recs, lo, hi, EE);
    }
  }
  // after fill: cursor[n] == row_off[n+1]  (row end)

  // ---- Degree-sorted node permutation (LDS-aggregated counting sort) ----
  hipMemsetAsync(dhist, 0, MAXDEG * sizeof(int), stream);
  dhist_k<<<ngrid, 256, 0, stream>>>(row_off, cursor, dhist);
  dscan_k<<<1, MAXDEG, 0, stream>>>(dhist);
  dperm_k<<<ngrid, 256, 0, stream>>>(row_off, cursor, dhist, perm);

  const int ggrid = (NN * 16 + 255) / 256;
  const int mgrid = (NN + 63) / 64;

  // ---- Layer 1 ----
  gather_k<<<ggrid, 256, 0, stream>>>(xb, row_off, cursor, recs, perm, aggrb);
  gemm_mfma_k<HH, true, true><<<mgrid, 256, 0, stream>>>(aggrb, xb, Wt1, br1, hb, NN);

  // ---- Layer 2 ----
  gather_k<<<ggrid, 256, 0, stream>>>(hb, row_off, cursor, recs, perm, aggrb);
  gemm_mfma_k<OO, false, false><<<mgrid, 256, 0, stream>>>(aggrb, hb, Wt2, br2, out, NN);
}

// Round 8
// 310.586 us; speedup vs baseline: 2.8438x; 1.1971x over previous
//
#include <hip/hip_runtime.h>

// Problem constants (from reference)
#define NN 100000
#define EE 1600000
#define DD 128   // input dim
#define HH 128   // hidden dim
#define OO 64    // output dim

#define NPART 8          // dst-range partitions for bucket fill (write locality)
#define MAXDEG 512       // degree-sort bins (degree >= 511 clamps)
#define CAP 48           // slots per node (P[deg>=48] ~ 1e-10 for Poisson(16))
#define MAX_OVF 4096     // overflow edge capacity (never hit in practice)

typedef unsigned short u16;
typedef __attribute__((ext_vector_type(8))) short bf16x8;  // 8 bf16 = 4 VGPR
typedef __attribute__((ext_vector_type(4))) float f32x4;

// ---------------------------------------------------------------------------
// bf16 helpers (RNE round, finite values only)
__device__ __forceinline__ u16 f2b(float f) {
  union { float f; unsigned u; } v; v.f = f;
  unsigned r = v.u + 0x7fffu + ((v.u >> 16) & 1u);
  return (u16)(r >> 16);
}
__device__ __forceinline__ float b2f(unsigned h) {
  union { unsigned u; float f; } v; v.u = h << 16;
  return v.f;
}
__device__ __forceinline__ void fma8(float* acc, uint4 v, float w) {
  acc[0] = fmaf(b2f(v.x & 0xffffu), w, acc[0]);
  acc[1] = fmaf(b2f(v.x >> 16), w, acc[1]);
  acc[2] = fmaf(b2f(v.y & 0xffffu), w, acc[2]);
  acc[3] = fmaf(b2f(v.y >> 16), w, acc[3]);
  acc[4] = fmaf(b2f(v.z & 0xffffu), w, acc[4]);
  acc[5] = fmaf(b2f(v.z >> 16), w, acc[5]);
  acc[6] = fmaf(b2f(v.w & 0xffffu), w, acc[6]);
  acc[7] = fmaf(b2f(v.w >> 16), w, acc[7]);
}

// ---------------------------------------------------------------------------
// Convert x [N,128] fp32 -> bf16 (8 elems per thread)
__global__ __launch_bounds__(256) void cvt_x_k(const float* __restrict__ x,
                                               u16* __restrict__ xb) {
  int i = blockIdx.x * 256 + threadIdx.x;  // chunk of 8 elems
  if (i >= NN * DD / 8) return;
  const float4* p = reinterpret_cast<const float4*>(x) + (size_t)i * 2;
  float4 a = p[0], b = p[1];
  uint4 o;
  o.x = (unsigned)f2b(a.x) | ((unsigned)f2b(a.y) << 16);
  o.y = (unsigned)f2b(a.z) | ((unsigned)f2b(a.w) << 16);
  o.z = (unsigned)f2b(b.x) | ((unsigned)f2b(b.y) << 16);
  o.w = (unsigned)f2b(b.z) | ((unsigned)f2b(b.w) << 16);
  reinterpret_cast<uint4*>(xb)[i] = o;
}

// ---------------------------------------------------------------------------
// Build stacked, transposed bf16 weights.
__global__ __launch_bounds__(256) void cvt_w_k(
    const float* __restrict__ Wr1, const float* __restrict__ Wo1,
    const float* __restrict__ Wr2, const float* __restrict__ Wo2,
    u16* __restrict__ Wt1, u16* __restrict__ Wt2) {
  int i = blockIdx.x * 256 + threadIdx.x;
  if (i < 128 * 256) {
    int n = i >> 8, k = i & 255;
    float v = (k < 128) ? Wr1[k * 128 + n] : Wo1[(k - 128) * 128 + n];
    Wt1[i] = f2b(v);
  } else if (i < 128 * 256 + 64 * 256) {
    int j = i - 128 * 256;
    int n = j >> 8, k = j & 255;
    float v = (k < 128) ? Wr2[k * 64 + n] : Wo2[(k - 128) * 64 + n];
    Wt2[j] = f2b(v);
  }
}

// ---------------------------------------------------------------------------
// Direct bucket fill (single atomic pass, dst-range partitioned for store
// locality). Record = uint2{ src, float_bits(sigmoid(w)) } at slots[dst*CAP+pos].
// Rare overflow (deg > CAP) goes to a compact list, applied post-gather.
__global__ __launch_bounds__(256) void fill_direct_k(
    const int* __restrict__ ei, const float* __restrict__ w,
    int* __restrict__ cnt, uint2* __restrict__ slots,
    uint4* __restrict__ ovf, int* __restrict__ ovf_cnt,
    int lo, int hi, int E) {
  int e = blockIdx.x * 256 + threadIdx.x;
  if (e >= E) return;
  int dst = ei[E + e];
  if (dst < lo || dst >= hi) return;
  int pos = atomicAdd(&cnt[dst], 1);
  float sig = 1.0f / (1.0f + expf(-w[e]));
  unsigned src = (unsigned)ei[e];
  if (pos < CAP) {
    slots[(size_t)dst * CAP + pos] = make_uint2(src, __float_as_uint(sig));
  } else {
    int o = atomicAdd(ovf_cnt, 1);
    if (o < MAX_OVF) ovf[o] = make_uint4((unsigned)dst, src, __float_as_uint(sig), 0u);
  }
}

// ---------------------------------------------------------------------------
// Degree counting sort with LDS pre-aggregation (histogram -> scan -> perm).
__global__ __launch_bounds__(256) void dhist_k(const int* __restrict__ cnt,
                                               int* __restrict__ dhist) {
  __shared__ int lh[MAXDEG];
  for (int i = threadIdx.x; i < MAXDEG; i += 256) lh[i] = 0;
  __syncthreads();
  int n = blockIdx.x * 256 + threadIdx.x;
  if (n < NN) {
    int d = min(cnt[n], MAXDEG - 1);
    atomicAdd(&lh[d], 1);
  }
  __syncthreads();
  for (int i = threadIdx.x; i < MAXDEG; i += 256) {
    int c = lh[i];
    if (c) atomicAdd(&dhist[i], c);
  }
}

__global__ __launch_bounds__(MAXDEG) void dscan_k(int* __restrict__ dhist) {
  __shared__ int s[MAXDEG];
  const int t = threadIdx.x;
  int v = dhist[t];
  s[t] = v;
  __syncthreads();
#pragma unroll
  for (int off = 1; off < MAXDEG; off <<= 1) {
    int u = (t >= off) ? s[t - off] : 0;
    __syncthreads();
    s[t] += u;
    __syncthreads();
  }
  dhist[t] = s[t] - v;  // exclusive (becomes bin cursor)
}

__global__ __launch_bounds__(256) void dperm_k(const int* __restrict__ cnt,
                                               int* __restrict__ dcur,
                                               int* __restrict__ perm) {
  __shared__ int lh[MAXDEG];
  __shared__ int lbase[MAXDEG];
  for (int i = threadIdx.x; i < MAXDEG; i += 256) lh[i] = 0;
  __syncthreads();
  int n = blockIdx.x * 256 + threadIdx.x;
  int d = 0, lpos = 0;
  if (n < NN) {
    d = min(cnt[n], MAXDEG - 1);
    lpos = atomicAdd(&lh[d], 1);
  }
  __syncthreads();
  for (int i = threadIdx.x; i < MAXDEG; i += 256) {
    int c = lh[i];
    if (c) lbase[i] = atomicAdd(&dcur[i], c);
  }
  __syncthreads();
  if (n < NN) perm[lbase[d] + lpos] = n;
}

// ---------------------------------------------------------------------------
// Aggregation as gather over bf16 features: 16 lanes per node, 8 bf16 each.
// Nodes in degree-sorted order (perm); bucket rows at slots[node*CAP].
__global__ __launch_bounds__(256) void gather_k(
    const u16* __restrict__ feat, const int* __restrict__ cnt,
    const uint2* __restrict__ slots, const int* __restrict__ perm,
    u16* __restrict__ aggr) {
  int gid = blockIdx.x * 256 + threadIdx.x;
  int g = gid >> 4;
  int c = gid & 15;  // 8-elem chunk
  if (g >= NN) return;
  int node = perm[g];
  int count = min(cnt[node], CAP);
  const uint2* recs = slots + (size_t)node * CAP;
  float acc[8] = {0.f, 0.f, 0.f, 0.f, 0.f, 0.f, 0.f, 0.f};
  int e = 0;
  for (; e + 4 <= count; e += 4) {
    uint2 r0 = recs[e + 0];
    uint2 r1 = recs[e + 1];
    uint2 r2 = recs[e + 2];
    uint2 r3 = recs[e + 3];
    uint4 v0 = *reinterpret_cast<const uint4*>(feat + (size_t)r0.x * DD + c * 8);
    uint4 v1 = *reinterpret_cast<const uint4*>(feat + (size_t)r1.x * DD + c * 8);
    uint4 v2 = *reinterpret_cast<const uint4*>(feat + (size_t)r2.x * DD + c * 8);
    uint4 v3 = *reinterpret_cast<const uint4*>(feat + (size_t)r3.x * DD + c * 8);
    fma8(acc, v0, __uint_as_float(r0.y));
    fma8(acc, v1, __uint_as_float(r1.y));
    fma8(acc, v2, __uint_as_float(r2.y));
    fma8(acc, v3, __uint_as_float(r3.y));
  }
  for (; e < count; ++e) {
    uint2 r = recs[e];
    uint4 v = *reinterpret_cast<const uint4*>(feat + (size_t)r.x * DD + c * 8);
    fma8(acc, v, __uint_as_float(r.y));
  }
  uint4 o;
  o.x = (unsigned)f2b(acc[0]) | ((unsigned)f2b(acc[1]) << 16);
  o.y = (unsigned)f2b(acc[2]) | ((unsigned)f2b(acc[3]) << 16);
  o.z = (unsigned)f2b(acc[4]) | ((unsigned)f2b(acc[5]) << 16);
  o.w = (unsigned)f2b(acc[6]) | ((unsigned)f2b(acc[7]) << 16);
  *reinterpret_cast<uint4*>(aggr + (size_t)node * DD + c * 8) = o;
}

// ---------------------------------------------------------------------------
// Apply rare overflow edges into aggr (bf16) via CAS add. No-op when empty.
__global__ __launch_bounds__(256) void ovf_fix_k(const int* __restrict__ ovf_cnt,
                                                 const uint4* __restrict__ ovf,
                                                 const u16* __restrict__ feat,
                                                 u16* __restrict__ aggr) {
  int novf = min(*ovf_cnt, MAX_OVF);
  int gid = blockIdx.x * 256 + threadIdx.x;
  int idx = gid >> 6;   // overflow edge
  int word = gid & 63;  // 2-bf16 word within 128 features
  if (idx >= novf) return;
  uint4 r = ovf[idx];
  float wgt = __uint_as_float(r.z);
  unsigned fv = *reinterpret_cast<const unsigned*>(feat + (size_t)r.y * DD + word * 2);
  float m0 = b2f(fv & 0xffffu) * wgt;
  float m1 = b2f(fv >> 16) * wgt;
  unsigned* addr = reinterpret_cast<unsigned*>(aggr + (size_t)r.x * DD + word * 2);
  unsigned old = *addr, assumed;
  do {
    assumed = old;
    float a0 = b2f(assumed & 0xffffu) + m0;
    float a1 = b2f(assumed >> 16) + m1;
    unsigned nv = (unsigned)f2b(a0) | ((unsigned)f2b(a1) << 16);
    old = atomicCAS(addr, assumed, nv);
  } while (old != assumed);
}

// ---------------------------------------------------------------------------
// MFMA dual-GEMM:  C = (relu?)( [A1 | A2] @ Bt^T + bias )
template <int HO, bool RELU, bool OUTBF16>
__global__ __launch_bounds__(256) void gemm_mfma_k(
    const u16* __restrict__ A1, const u16* __restrict__ A2,
    const u16* __restrict__ Bt, const float* __restrict__ bias,
    void* __restrict__ Cout, int n_rows) {
  constexpr int CG = HO / 16;
  __shared__ u16 As[64][40];
  __shared__ u16 Bs[HO][40];

  const int t = threadIdx.x;
  const int w = t >> 6;
  const int lane = t & 63;
  const int row0 = blockIdx.x * 64;

  f32x4 acc[CG];
#pragma unroll
  for (int cg = 0; cg < CG; ++cg) acc[cg] = (f32x4){0.f, 0.f, 0.f, 0.f};

  const int arow = w * 16 + (lane & 15);
  const int kq = (lane >> 4) * 8;

  for (int k0 = 0; k0 < 256; k0 += 32) {
    {
      int node = t >> 2;
      int koff = (t & 3) * 8;
      int k = k0 + koff;
      int gr = row0 + node;
      uint4 v = make_uint4(0u, 0u, 0u, 0u);
      if (gr < n_rows) {
        const u16* src = (k < 128) ? (A1 + (size_t)gr * 128 + k)
                                   : (A2 + (size_t)gr * 128 + (k - 128));
        v = *reinterpret_cast<const uint4*>(src);
      }
      *reinterpret_cast<uint4*>(&As[node][koff]) = v;
    }
#pragma unroll
    for (int i = 0; i < CG / 4; ++i) {
      int c2 = t + i * 256;
      int n = c2 >> 2;
      int koff = (c2 & 3) * 8;
      uint4 v = *reinterpret_cast<const uint4*>(Bt + (size_t)n * 256 + k0 + koff);
      *reinterpret_cast<uint4*>(&Bs[n][koff]) = v;
    }
    __syncthreads();

    bf16x8 a = *reinterpret_cast<const bf16x8*>(&As[arow][kq]);
#pragma unroll
    for (int cg = 0; cg < CG; ++cg) {
      bf16x8 b = *reinterpret_cast<const bf16x8*>(&Bs[cg * 16 + (lane & 15)][kq]);
      acc[cg] = __builtin_amdgcn_mfma_f32_16x16x32_bf16(a, b, acc[cg], 0, 0, 0);
    }
    __syncthreads();
  }

  const int rbase = w * 16 + ((lane >> 4) << 2);
#pragma unroll
  for (int cg = 0; cg < CG; ++cg) {
    int col = cg * 16 + (lane & 15);
    float bia = bias[col];
#pragma unroll
    for (int j = 0; j < 4; ++j) {
      int gr = row0 + rbase + j;
      if (gr < n_rows) {
        float v = acc[cg][j] + bia;
        if (RELU) v = fmaxf(v, 0.f);
        if (OUTBF16) ((u16*)Cout)[(size_t)gr * HO + col] = f2b(v);
        else ((float*)Cout)[(size_t)gr * HO + col] = v;
      }
    }
  }
}

// ---------------------------------------------------------------------------
extern "C" void kernel_launch(void* const* d_in, const int* in_sizes, int n_in,
                              void* d_out, int out_size, void* d_ws, size_t ws_size,
                              hipStream_t stream) {
  const float* x   = (const float*)d_in[0];
  const float* w   = (const float*)d_in[1];
  const int*   ei  = (const int*)d_in[2];   // [2, E]: row0=src, row1=dst
  const float* Wr1 = (const float*)d_in[3];
  const float* br1 = (const float*)d_in[4];
  const float* Wo1 = (const float*)d_in[5];
  const float* Wr2 = (const float*)d_in[6];
  const float* br2 = (const float*)d_in[7];
  const float* Wo2 = (const float*)d_in[8];
  float* out = (float*)d_out;

  // Workspace layout (bytes, all offsets 16B-aligned):
  char* ws = (char*)d_ws;
  int*   cnt     = (int*)(ws);                        // N ints           400,000
  int*   ovf_cnt = (int*)(ws + 400000);               // 1 int (+pad)       1,024
  int*   dhist   = (int*)(ws + 401024);               // 512 ints           2,048
  int*   perm    = (int*)(ws + 403072);               // N ints           400,000
  uint4* ovf     = (uint4*)(ws + 803072);             // 4096 x 16B        65,536
  uint2* slots   = (uint2*)(ws + 868608);             // N*CAP*8B      38,400,000
  u16*   xb      = (u16*)(ws + 39268608);             // N*128 bf16    25,600,000
  u16*   hb      = (u16*)(ws + 64868608);             // N*128 bf16    25,600,000
  u16*   aggrb   = (u16*)(ws + 90468608);             // N*128 bf16    25,600,000
  u16*   Wt1     = (u16*)(ws + 116068608);            // 128*256 bf16      65,536
  u16*   Wt2     = (u16*)(ws + 116134144);            // 64*256 bf16       32,768
  // total ~116.2 MB

  const int egrid = (EE + 255) / 256;
  const int ngrid = (NN + 255) / 256;

  // ---- Prep: bf16 conversions ----
  cvt_x_k<<<NN * DD / 8 / 256, 256, 0, stream>>>(x, xb);
  cvt_w_k<<<(192 * 256 + 255) / 256, 256, 0, stream>>>(Wr1, Wo1, Wr2, Wo2, Wt1, Wt2);

  // ---- Build dst-buckets directly (single atomic pass, partitioned) ----
  hipMemsetAsync(cnt, 0, 403072, stream);  // zeroes cnt + ovf_cnt + dhist
  {
    const int pstep = (NN + NPART - 1) / NPART;
    for (int p = 0; p < NPART; ++p) {
      int lo = p * pstep;
      int hi = min(NN, lo + pstep);
      fill_direct_k<<<egrid, 256, 0, stream>>>(ei, w, cnt, slots, ovf, ovf_cnt, lo, hi, EE);
    }
  }

  // ---- Degree-sorted node permutation (LDS-aggregated counting sort) ----
  dhist_k<<<ngrid, 256, 0, stream>>>(cnt, dhist);
  dscan_k<<<1, MAXDEG, 0, stream>>>(dhist);
  dperm_k<<<ngrid, 256, 0, stream>>>(cnt, dhist, perm);

  const int ggrid = (NN * 16 + 255) / 256;
  const int mgrid = (NN + 63) / 64;
  const int ogrid = (MAX_OVF * 64) / 256;

  // ---- Layer 1 ----
  gather_k<<<ggrid, 256, 0, stream>>>(xb, cnt, slots, perm, aggrb);
  ovf_fix_k<<<ogrid, 256, 0, stream>>>(ovf_cnt, ovf, xb, aggrb);
  gemm_mfma_k<HH, true, true><<<mgrid, 256, 0, stream>>>(aggrb, xb, Wt1, br1, hb, NN);

  // ---- Layer 2 ----
  gather_k<<<ggrid, 256, 0, stream>>>(hb, cnt, slots, perm, aggrb);
  ovf_fix_k<<<ogrid, 256, 0, stream>>>(ovf_cnt, ovf, hb, aggrb);
  gemm_mfma_k<OO, false, false><<<mgrid, 256, 0, stream>>>(aggrb, hb, Wt2, br2, out, NN);
}

// Round 9
// 295.963 us; speedup vs baseline: 2.9844x; 1.0494x over previous
//
#include <hip/hip_runtime.h>

// Problem constants (from reference)
#define NN 100000
#define EE 1600000
#define DD 128   // input dim
#define HH 128   // hidden dim
#define OO 64    // output dim

#define NPART 4          // dst-range partitions for bucket fill (write locality)
#define MAXDEG 512       // degree-sort bins (degree >= 511 clamps)
#define CAP 32           // slots per node (P[Poisson(16)>=32] ~ 1e-4; overflow path below)
#define MAX_OVF 16384    // overflow edge capacity
#define CSTRIDE 16       // cnt padding: 16 ints = 64B line per node (atomic line-parallelism)

typedef unsigned short u16;
typedef __attribute__((ext_vector_type(8))) short bf16x8;  // 8 bf16 = 4 VGPR
typedef __attribute__((ext_vector_type(4))) float f32x4;

// ---------------------------------------------------------------------------
// bf16 helpers (RNE round, finite values only)
__device__ __forceinline__ u16 f2b(float f) {
  union { float f; unsigned u; } v; v.f = f;
  unsigned r = v.u + 0x7fffu + ((v.u >> 16) & 1u);
  return (u16)(r >> 16);
}
__device__ __forceinline__ float b2f(unsigned h) {
  union { unsigned u; float f; } v; v.u = h << 16;
  return v.f;
}
__device__ __forceinline__ void fma8(float* acc, uint4 v, float w) {
  acc[0] = fmaf(b2f(v.x & 0xffffu), w, acc[0]);
  acc[1] = fmaf(b2f(v.x >> 16), w, acc[1]);
  acc[2] = fmaf(b2f(v.y & 0xffffu), w, acc[2]);
  acc[3] = fmaf(b2f(v.y >> 16), w, acc[3]);
  acc[4] = fmaf(b2f(v.z & 0xffffu), w, acc[4]);
  acc[5] = fmaf(b2f(v.z >> 16), w, acc[5]);
  acc[6] = fmaf(b2f(v.w & 0xffffu), w, acc[6]);
  acc[7] = fmaf(b2f(v.w >> 16), w, acc[7]);
}

// ---------------------------------------------------------------------------
// Convert x [N,128] fp32 -> bf16 (8 elems per thread)
__global__ __launch_bounds__(256) void cvt_x_k(const float* __restrict__ x,
                                               u16* __restrict__ xb) {
  int i = blockIdx.x * 256 + threadIdx.x;  // chunk of 8 elems
  if (i >= NN * DD / 8) return;
  const float4* p = reinterpret_cast<const float4*>(x) + (size_t)i * 2;
  float4 a = p[0], b = p[1];
  uint4 o;
  o.x = (unsigned)f2b(a.x) | ((unsigned)f2b(a.y) << 16);
  o.y = (unsigned)f2b(a.z) | ((unsigned)f2b(a.w) << 16);
  o.z = (unsigned)f2b(b.x) | ((unsigned)f2b(b.y) << 16);
  o.w = (unsigned)f2b(b.z) | ((unsigned)f2b(b.w) << 16);
  reinterpret_cast<uint4*>(xb)[i] = o;
}

// ---------------------------------------------------------------------------
// Build stacked, transposed bf16 weights.
__global__ __launch_bounds__(256) void cvt_w_k(
    const float* __restrict__ Wr1, const float* __restrict__ Wo1,
    const float* __restrict__ Wr2, const float* __restrict__ Wo2,
    u16* __restrict__ Wt1, u16* __restrict__ Wt2) {
  int i = blockIdx.x * 256 + threadIdx.x;
  if (i < 128 * 256) {
    int n = i >> 8, k = i & 255;
    float v = (k < 128) ? Wr1[k * 128 + n] : Wo1[(k - 128) * 128 + n];
    Wt1[i] = f2b(v);
  } else if (i < 128 * 256 + 64 * 256) {
    int j = i - 128 * 256;
    int n = j >> 8, k = j & 255;
    float v = (k < 128) ? Wr2[k * 64 + n] : Wo2[(k - 128) * 64 + n];
    Wt2[j] = f2b(v);
  }
}

// ---------------------------------------------------------------------------
// Direct bucket fill (single atomic pass over dst-partitions). cnt is padded
// to one node per 64B line so the per-edge returning atomics hit ~100k
// independent lines (TCC channel parallelism) instead of serializing 256/line.
__global__ __launch_bounds__(256) void fill_direct_k(
    const int* __restrict__ ei, const float* __restrict__ w,
    int* __restrict__ cntp, uint2* __restrict__ slots,
    uint4* __restrict__ ovf, int* __restrict__ ovf_cnt,
    int lo, int hi, int E) {
  int e = blockIdx.x * 256 + threadIdx.x;
  if (e >= E) return;
  int dst = ei[E + e];
  if (dst < lo || dst >= hi) return;
  int pos = atomicAdd(&cntp[dst * CSTRIDE], 1);
  float sig = 1.0f / (1.0f + expf(-w[e]));
  unsigned src = (unsigned)ei[e];
  if (pos < CAP) {
    slots[(size_t)dst * CAP + pos] = make_uint2(src, __float_as_uint(sig));
  } else {
    int o = atomicAdd(ovf_cnt, 1);
    if (o < MAX_OVF) ovf[o] = make_uint4((unsigned)dst, src, __float_as_uint(sig), 0u);
  }
}

// ---------------------------------------------------------------------------
// Degree counting sort with LDS pre-aggregation (histogram -> scan -> perm).
__global__ __launch_bounds__(256) void dhist_k(const int* __restrict__ cntp,
                                               int* __restrict__ dhist) {
  __shared__ int lh[MAXDEG];
  for (int i = threadIdx.x; i < MAXDEG; i += 256) lh[i] = 0;
  __syncthreads();
  int n = blockIdx.x * 256 + threadIdx.x;
  if (n < NN) {
    int d = min(cntp[n * CSTRIDE], MAXDEG - 1);
    atomicAdd(&lh[d], 1);
  }
  __syncthreads();
  for (int i = threadIdx.x; i < MAXDEG; i += 256) {
    int c = lh[i];
    if (c) atomicAdd(&dhist[i], c);
  }
}

__global__ __launch_bounds__(MAXDEG) void dscan_k(int* __restrict__ dhist) {
  __shared__ int s[MAXDEG];
  const int t = threadIdx.x;
  int v = dhist[t];
  s[t] = v;
  __syncthreads();
#pragma unroll
  for (int off = 1; off < MAXDEG; off <<= 1) {
    int u = (t >= off) ? s[t - off] : 0;
    __syncthreads();
    s[t] += u;
    __syncthreads();
  }
  dhist[t] = s[t] - v;  // exclusive (becomes bin cursor)
}

__global__ __launch_bounds__(256) void dperm_k(const int* __restrict__ cntp,
                                               int* __restrict__ dcur,
                                               int* __restrict__ perm) {
  __shared__ int lh[MAXDEG];
  __shared__ int lbase[MAXDEG];
  for (int i = threadIdx.x; i < MAXDEG; i += 256) lh[i] = 0;
  __syncthreads();
  int n = blockIdx.x * 256 + threadIdx.x;
  int d = 0, lpos = 0;
  if (n < NN) {
    d = min(cntp[n * CSTRIDE], MAXDEG - 1);
    lpos = atomicAdd(&lh[d], 1);
  }
  __syncthreads();
  for (int i = threadIdx.x; i < MAXDEG; i += 256) {
    int c = lh[i];
    if (c) lbase[i] = atomicAdd(&dcur[i], c);
  }
  __syncthreads();
  if (n < NN) perm[lbase[d] + lpos] = n;
}

// ---------------------------------------------------------------------------
// Aggregation as gather over bf16 features: 16 lanes per node, 8 bf16 each.
// Nodes in degree-sorted order (perm); edge loop unrolled x8 for MLP.
__global__ __launch_bounds__(256) void gather_k(
    const u16* __restrict__ feat, const int* __restrict__ cntp,
    const uint2* __restrict__ slots, const int* __restrict__ perm,
    u16* __restrict__ aggr) {
  int gid = blockIdx.x * 256 + threadIdx.x;
  int g = gid >> 4;
  int c = gid & 15;  // 8-elem chunk
  if (g >= NN) return;
  int node = perm[g];
  int count = min(cntp[node * CSTRIDE], CAP);
  const uint2* recs = slots + (size_t)node * CAP;
  float acc[8] = {0.f, 0.f, 0.f, 0.f, 0.f, 0.f, 0.f, 0.f};
  int e = 0;
  for (; e + 8 <= count; e += 8) {
    uint2 r[8];
#pragma unroll
    for (int j = 0; j < 8; ++j) r[j] = recs[e + j];
    uint4 v[8];
#pragma unroll
    for (int j = 0; j < 8; ++j)
      v[j] = *reinterpret_cast<const uint4*>(feat + (size_t)r[j].x * DD + c * 8);
#pragma unroll
    for (int j = 0; j < 8; ++j) fma8(acc, v[j], __uint_as_float(r[j].y));
  }
  if (e + 4 <= count) {
    uint2 r[4];
#pragma unroll
    for (int j = 0; j < 4; ++j) r[j] = recs[e + j];
    uint4 v[4];
#pragma unroll
    for (int j = 0; j < 4; ++j)
      v[j] = *reinterpret_cast<const uint4*>(feat + (size_t)r[j].x * DD + c * 8);
#pragma unroll
    for (int j = 0; j < 4; ++j) fma8(acc, v[j], __uint_as_float(r[j].y));
    e += 4;
  }
  for (; e < count; ++e) {
    uint2 r = recs[e];
    uint4 v = *reinterpret_cast<const uint4*>(feat + (size_t)r.x * DD + c * 8);
    fma8(acc, v, __uint_as_float(r.y));
  }
  uint4 o;
  o.x = (unsigned)f2b(acc[0]) | ((unsigned)f2b(acc[1]) << 16);
  o.y = (unsigned)f2b(acc[2]) | ((unsigned)f2b(acc[3]) << 16);
  o.z = (unsigned)f2b(acc[4]) | ((unsigned)f2b(acc[5]) << 16);
  o.w = (unsigned)f2b(acc[6]) | ((unsigned)f2b(acc[7]) << 16);
  *reinterpret_cast<uint4*>(aggr + (size_t)node * DD + c * 8) = o;
}

// ---------------------------------------------------------------------------
// Apply rare overflow edges into aggr (bf16) via CAS add. No-op when empty.
__global__ __launch_bounds__(256) void ovf_fix_k(const int* __restrict__ ovf_cnt,
                                                 const uint4* __restrict__ ovf,
                                                 const u16* __restrict__ feat,
                                                 u16* __restrict__ aggr) {
  int novf = min(*ovf_cnt, MAX_OVF);
  int gid = blockIdx.x * 256 + threadIdx.x;
  int idx = gid >> 6;   // overflow edge
  int word = gid & 63;  // 2-bf16 word within 128 features
  if (idx >= novf) return;
  uint4 r = ovf[idx];
  float wgt = __uint_as_float(r.z);
  unsigned fv = *reinterpret_cast<const unsigned*>(feat + (size_t)r.y * DD + word * 2);
  float m0 = b2f(fv & 0xffffu) * wgt;
  float m1 = b2f(fv >> 16) * wgt;
  unsigned* addr = reinterpret_cast<unsigned*>(aggr + (size_t)r.x * DD + word * 2);
  unsigned old = *addr, assumed;
  do {
    assumed = old;
    float a0 = b2f(assumed & 0xffffu) + m0;
    float a1 = b2f(assumed >> 16) + m1;
    unsigned nv = (unsigned)f2b(a0) | ((unsigned)f2b(a1) << 16);
    old = atomicCAS(addr, assumed, nv);
  } while (old != assumed);
}

// ---------------------------------------------------------------------------
// MFMA dual-GEMM:  C = (relu?)( [A1 | A2] @ Bt^T + bias )
template <int HO, bool RELU, bool OUTBF16>
__global__ __launch_bounds__(256) void gemm_mfma_k(
    const u16* __restrict__ A1, const u16* __restrict__ A2,
    const u16* __restrict__ Bt, const float* __restrict__ bias,
    void* __restrict__ Cout, int n_rows) {
  constexpr int CG = HO / 16;
  __shared__ u16 As[64][40];
  __shared__ u16 Bs[HO][40];

  const int t = threadIdx.x;
  const int w = t >> 6;
  const int lane = t & 63;
  const int row0 = blockIdx.x * 64;

  f32x4 acc[CG];
#pragma unroll
  for (int cg = 0; cg < CG; ++cg) acc[cg] = (f32x4){0.f, 0.f, 0.f, 0.f};

  const int arow = w * 16 + (lane & 15);
  const int kq = (lane >> 4) * 8;

  for (int k0 = 0; k0 < 256; k0 += 32) {
    {
      int node = t >> 2;
      int koff = (t & 3) * 8;
      int k = k0 + koff;
      int gr = row0 + node;
      uint4 v = make_uint4(0u, 0u, 0u, 0u);
      if (gr < n_rows) {
        const u16* src = (k < 128) ? (A1 + (size_t)gr * 128 + k)
                                   : (A2 + (size_t)gr * 128 + (k - 128));
        v = *reinterpret_cast<const uint4*>(src);
      }
      *reinterpret_cast<uint4*>(&As[node][koff]) = v;
    }
#pragma unroll
    for (int i = 0; i < CG / 4; ++i) {
      int c2 = t + i * 256;
      int n = c2 >> 2;
      int koff = (c2 & 3) * 8;
      uint4 v = *reinterpret_cast<const uint4*>(Bt + (size_t)n * 256 + k0 + koff);
      *reinterpret_cast<uint4*>(&Bs[n][koff]) = v;
    }
    __syncthreads();

    bf16x8 a = *reinterpret_cast<const bf16x8*>(&As[arow][kq]);
#pragma unroll
    for (int cg = 0; cg < CG; ++cg) {
      bf16x8 b = *reinterpret_cast<const bf16x8*>(&Bs[cg * 16 + (lane & 15)][kq]);
      acc[cg] = __builtin_amdgcn_mfma_f32_16x16x32_bf16(a, b, acc[cg], 0, 0, 0);
    }
    __syncthreads();
  }

  const int rbase = w * 16 + ((lane >> 4) << 2);
#pragma unroll
  for (int cg = 0; cg < CG; ++cg) {
    int col = cg * 16 + (lane & 15);
    float bia = bias[col];
#pragma unroll
    for (int j = 0; j < 4; ++j) {
      int gr = row0 + rbase + j;
      if (gr < n_rows) {
        float v = acc[cg][j] + bia;
        if (RELU) v = fmaxf(v, 0.f);
        if (OUTBF16) ((u16*)Cout)[(size_t)gr * HO + col] = f2b(v);
        else ((float*)Cout)[(size_t)gr * HO + col] = v;
      }
    }
  }
}

// ---------------------------------------------------------------------------
extern "C" void kernel_launch(void* const* d_in, const int* in_sizes, int n_in,
                              void* d_out, int out_size, void* d_ws, size_t ws_size,
                              hipStream_t stream) {
  const float* x   = (const float*)d_in[0];
  const float* w   = (const float*)d_in[1];
  const int*   ei  = (const int*)d_in[2];   // [2, E]: row0=src, row1=dst
  const float* Wr1 = (const float*)d_in[3];
  const float* br1 = (const float*)d_in[4];
  const float* Wo1 = (const float*)d_in[5];
  const float* Wr2 = (const float*)d_in[6];
  const float* br2 = (const float*)d_in[7];
  const float* Wo2 = (const float*)d_in[8];
  float* out = (float*)d_out;

  // Workspace layout (bytes, all offsets 16B-aligned):
  char* ws = (char*)d_ws;
  int*   cntp    = (int*)(ws);                        // N*16 ints      6,400,000
  int*   ovf_cnt = (int*)(ws + 6400000);              // 1 int (+pad)       1,024
  int*   dhist   = (int*)(ws + 6401024);              // 512 ints           2,048
  int*   perm    = (int*)(ws + 6403072);              // N ints           400,000
  uint4* ovf     = (uint4*)(ws + 6803072);            // 16384 x 16B      262,144
  uint2* slots   = (uint2*)(ws + 7065216);            // N*CAP*8B      25,600,000
  u16*   xb      = (u16*)(ws + 32665216);             // N*128 bf16    25,600,000
  u16*   hb      = (u16*)(ws + 58265216);             // N*128 bf16    25,600,000
  u16*   aggrb   = (u16*)(ws + 83865216);             // N*128 bf16    25,600,000
  u16*   Wt1     = (u16*)(ws + 109465216);            // 128*256 bf16      65,536
  u16*   Wt2     = (u16*)(ws + 109530752);            // 64*256 bf16       32,768
  // total ~109.6 MB

  const int egrid = (EE + 255) / 256;
  const int ngrid = (NN + 255) / 256;

  // ---- Prep: bf16 conversions ----
  cvt_x_k<<<NN * DD / 8 / 256, 256, 0, stream>>>(x, xb);
  cvt_w_k<<<(192 * 256 + 255) / 256, 256, 0, stream>>>(Wr1, Wo1, Wr2, Wo2, Wt1, Wt2);

  // ---- Build dst-buckets directly (single atomic pass, partitioned) ----
  hipMemsetAsync(cntp, 0, 6403072, stream);  // zeroes cntp + ovf_cnt + dhist
  {
    const int pstep = (NN + NPART - 1) / NPART;
    for (int p = 0; p < NPART; ++p) {
      int lo = p * pstep;
      int hi = min(NN, lo + pstep);
      fill_direct_k<<<egrid, 256, 0, stream>>>(ei, w, cntp, slots, ovf, ovf_cnt, lo, hi, EE);
    }
  }

  // ---- Degree-sorted node permutation (LDS-aggregated counting sort) ----
  dhist_k<<<ngrid, 256, 0, stream>>>(cntp, dhist);
  dscan_k<<<1, MAXDEG, 0, stream>>>(dhist);
  dperm_k<<<ngrid, 256, 0, stream>>>(cntp, dhist, perm);

  const int ggrid = (NN * 16 + 255) / 256;
  const int mgrid = (NN + 63) / 64;
  const int ogrid = (MAX_OVF * 64) / 256;

  // ---- Layer 1 ----
  gather_k<<<ggrid, 256, 0, stream>>>(xb, cntp, slots, perm, aggrb);
  ovf_fix_k<<<ogrid, 256, 0, stream>>>(ovf_cnt, ovf, xb, aggrb);
  gemm_mfma_k<HH, true, true><<<mgrid, 256, 0, stream>>>(aggrb, xb, Wt1, br1, hb, NN);

  // ---- Layer 2 ----
  gather_k<<<ggrid, 256, 0, stream>>>(hb, cntp, slots, perm, aggrb);
  ovf_fix_k<<<ogrid, 256, 0, stream>>>(ovf_cnt, ovf, hb, aggrb);
  gemm_mfma_k<OO, false, false><<<mgrid, 256, 0, stream>>>(aggrb, hb, Wt2, br2, out, NN);
}

// Round 12
// 276.740 us; speedup vs baseline: 3.1916x; 1.0695x over previous
//
#include <hip/hip_runtime.h>

// Problem constants (from reference)
#define NN 100000
#define EE 1600000
#define DD 128   // input dim
#define HH 128   // hidden dim
#define OO 64    // output dim

#define NPART 4          // dst-range partitions for bucket fill (write locality)
#define CAP 32           // slots per node (deg>32 handled by ovf path, proven r8/r9)
#define MAX_OVF 16384    // overflow edge capacity
#define CSTRIDE 16       // cnt padding: 16 ints = 64B line per node (atomic line-parallelism)

typedef unsigned short u16;
typedef __attribute__((ext_vector_type(8))) short bf16x8;  // 8 bf16 = 4 VGPR
typedef __attribute__((ext_vector_type(4))) float f32x4;

// ---------------------------------------------------------------------------
// bf16 helpers (RNE round, finite values only)
__device__ __forceinline__ u16 f2b(float f) {
  union { float f; unsigned u; } v; v.f = f;
  unsigned r = v.u + 0x7fffu + ((v.u >> 16) & 1u);
  return (u16)(r >> 16);
}
__device__ __forceinline__ float b2f(unsigned h) {
  union { unsigned u; float f; } v; v.u = h << 16;
  return v.f;
}
__device__ __forceinline__ void fma8(float* acc, uint4 v, float w) {
  acc[0] = fmaf(b2f(v.x & 0xffffu), w, acc[0]);
  acc[1] = fmaf(b2f(v.x >> 16), w, acc[1]);
  acc[2] = fmaf(b2f(v.y & 0xffffu), w, acc[2]);
  acc[3] = fmaf(b2f(v.y >> 16), w, acc[3]);
  acc[4] = fmaf(b2f(v.z & 0xffffu), w, acc[4]);
  acc[5] = fmaf(b2f(v.z >> 16), w, acc[5]);
  acc[6] = fmaf(b2f(v.w & 0xffffu), w, acc[6]);
  acc[7] = fmaf(b2f(v.w >> 16), w, acc[7]);
}

// ---------------------------------------------------------------------------
// Convert x [N,128] fp32 -> bf16 (8 elems per thread)
__global__ __launch_bounds__(256) void cvt_x_k(const float* __restrict__ x,
                                               u16* __restrict__ xb) {
  int i = blockIdx.x * 256 + threadIdx.x;  // chunk of 8 elems
  if (i >= NN * DD / 8) return;
  const float4* p = reinterpret_cast<const float4*>(x) + (size_t)i * 2;
  float4 a = p[0], b = p[1];
  uint4 o;
  o.x = (unsigned)f2b(a.x) | ((unsigned)f2b(a.y) << 16);
  o.y = (unsigned)f2b(a.z) | ((unsigned)f2b(a.w) << 16);
  o.z = (unsigned)f2b(b.x) | ((unsigned)f2b(b.y) << 16);
  o.w = (unsigned)f2b(b.z) | ((unsigned)f2b(b.w) << 16);
  reinterpret_cast<uint4*>(xb)[i] = o;
}

// ---------------------------------------------------------------------------
// Build stacked, transposed bf16 weights.
__global__ __launch_bounds__(256) void cvt_w_k(
    const float* __restrict__ Wr1, const float* __restrict__ Wo1,
    const float* __restrict__ Wr2, const float* __restrict__ Wo2,
    u16* __restrict__ Wt1, u16* __restrict__ Wt2) {
  int i = blockIdx.x * 256 + threadIdx.x;
  if (i < 128 * 256) {
    int n = i >> 8, k = i & 255;
    float v = (k < 128) ? Wr1[k * 128 + n] : Wo1[(k - 128) * 128 + n];
    Wt1[i] = f2b(v);
  } else if (i < 128 * 256 + 64 * 256) {
    int j = i - 128 * 256;
    int n = j >> 8, k = j & 255;
    float v = (k < 128) ? Wr2[k * 64 + n] : Wo2[(k - 128) * 64 + n];
    Wt2[j] = f2b(v);
  }
}

// ---------------------------------------------------------------------------
// Direct bucket fill (single atomic pass over dst-partitions). cnt is padded
// to one node per 64B line so the per-edge returning atomics hit ~100k
// independent lines (TCC channel parallelism) instead of serializing 256/line.
__global__ __launch_bounds__(256) void fill_direct_k(
    const int* __restrict__ ei, const float* __restrict__ w,
    int* __restrict__ cntp, uint2* __restrict__ slots,
    uint4* __restrict__ ovf, int* __restrict__ ovf_cnt,
    int lo, int hi, int E) {
  int e = blockIdx.x * 256 + threadIdx.x;
  if (e >= E) return;
  int dst = ei[E + e];
  if (dst < lo || dst >= hi) return;
  int pos = atomicAdd(&cntp[dst * CSTRIDE], 1);
  float sig = 1.0f / (1.0f + expf(-w[e]));
  unsigned src = (unsigned)ei[e];
  if (pos < CAP) {
    slots[(size_t)dst * CAP + pos] = make_uint2(src, __float_as_uint(sig));
  } else {
    int o = atomicAdd(ovf_cnt, 1);
    if (o < MAX_OVF) ovf[o] = make_uint4((unsigned)dst, src, __float_as_uint(sig), 0u);
  }
}

// ---------------------------------------------------------------------------
// Aggregation as gather over bf16 features: 16 lanes per node, 8 bf16 each.
// Natural node order (perm removed; it was a measured null). Edge loop
// unrolled x8 for memory-level parallelism.
__global__ __launch_bounds__(256) void gather_k(
    const u16* __restrict__ feat, const int* __restrict__ cntp,
    const uint2* __restrict__ slots, u16* __restrict__ aggr) {
  int gid = blockIdx.x * 256 + threadIdx.x;
  int node = gid >> 4;
  int c = gid & 15;  // 8-elem chunk
  if (node >= NN) return;
  int count = min(cntp[node * CSTRIDE], CAP);
  const uint2* recs = slots + (size_t)node * CAP;
  float acc[8] = {0.f, 0.f, 0.f, 0.f, 0.f, 0.f, 0.f, 0.f};
  int e = 0;
  for (; e + 8 <= count; e += 8) {
    uint2 r[8];
#pragma unroll
    for (int j = 0; j < 8; ++j) r[j] = recs[e + j];
    uint4 v[8];
#pragma unroll
    for (int j = 0; j < 8; ++j)
      v[j] = *reinterpret_cast<const uint4*>(feat + (size_t)r[j].x * DD + c * 8);
#pragma unroll
    for (int j = 0; j < 8; ++j) fma8(acc, v[j], __uint_as_float(r[j].y));
  }
  if (e + 4 <= count) {
    uint2 r[4];
#pragma unroll
    for (int j = 0; j < 4; ++j) r[j] = recs[e + j];
    uint4 v[4];
#pragma unroll
    for (int j = 0; j < 4; ++j)
      v[j] = *reinterpret_cast<const uint4*>(feat + (size_t)r[j].x * DD + c * 8);
#pragma unroll
    for (int j = 0; j < 4; ++j) fma8(acc, v[j], __uint_as_float(r[j].y));
    e += 4;
  }
  for (; e < count; ++e) {
    uint2 r = recs[e];
    uint4 v = *reinterpret_cast<const uint4*>(feat + (size_t)r.x * DD + c * 8);
    fma8(acc, v, __uint_as_float(r.y));
  }
  uint4 o;
  o.x = (unsigned)f2b(acc[0]) | ((unsigned)f2b(acc[1]) << 16);
  o.y = (unsigned)f2b(acc[2]) | ((unsigned)f2b(acc[3]) << 16);
  o.z = (unsigned)f2b(acc[4]) | ((unsigned)f2b(acc[5]) << 16);
  o.w = (unsigned)f2b(acc[6]) | ((unsigned)f2b(acc[7]) << 16);
  *reinterpret_cast<uint4*>(aggr + (size_t)node * DD + c * 8) = o;
}

// ---------------------------------------------------------------------------
// Apply rare overflow edges into aggr (bf16) via CAS add. No-op when empty.
// (Proven in rounds 8/9 with overflow exercised.)
__global__ __launch_bounds__(256) void ovf_fix_k(const int* __restrict__ ovf_cnt,
                                                 const uint4* __restrict__ ovf,
                                                 const u16* __restrict__ feat,
                                                 u16* __restrict__ aggr) {
  int novf = min(*ovf_cnt, MAX_OVF);
  int gid = blockIdx.x * 256 + threadIdx.x;
  int idx = gid >> 6;   // overflow edge
  int word = gid & 63;  // 2-bf16 word within 128 features
  if (idx >= novf) return;
  uint4 r = ovf[idx];
  float wgt = __uint_as_float(r.z);
  unsigned fv = *reinterpret_cast<const unsigned*>(feat + (size_t)r.y * DD + word * 2);
  float m0 = b2f(fv & 0xffffu) * wgt;
  float m1 = b2f(fv >> 16) * wgt;
  unsigned* addr = reinterpret_cast<unsigned*>(aggr + (size_t)r.x * DD + word * 2);
  unsigned old = *addr, assumed;
  do {
    assumed = old;
    float a0 = b2f(assumed & 0xffffu) + m0;
    float a1 = b2f(assumed >> 16) + m1;
    unsigned nv = (unsigned)f2b(a0) | ((unsigned)f2b(a1) << 16);
    old = atomicCAS(addr, assumed, nv);
  } while (old != assumed);
}

// ---------------------------------------------------------------------------
// MFMA dual-GEMM:  C = (relu?)( [A1 | A2] @ Bt^T + bias )
template <int HO, bool RELU, bool OUTBF16>
__global__ __launch_bounds__(256) void gemm_mfma_k(
    const u16* __restrict__ A1, const u16* __restrict__ A2,
    const u16* __restrict__ Bt, const float* __restrict__ bias,
    void* __restrict__ Cout, int n_rows) {
  constexpr int CG = HO / 16;
  __shared__ u16 As[64][40];
  __shared__ u16 Bs[HO][40];

  const int t = threadIdx.x;
  const int w = t >> 6;
  const int lane = t & 63;
  const int row0 = blockIdx.x * 64;

  f32x4 acc[CG];
#pragma unroll
  for (int cg = 0; cg < CG; ++cg) acc[cg] = (f32x4){0.f, 0.f, 0.f, 0.f};

  const int arow = w * 16 + (lane & 15);
  const int kq = (lane >> 4) * 8;

  for (int k0 = 0; k0 < 256; k0 += 32) {
    {
      int node = t >> 2;
      int koff = (t & 3) * 8;
      int k = k0 + koff;
      int gr = row0 + node;
      uint4 v = make_uint4(0u, 0u, 0u, 0u);
      if (gr < n_rows) {
        const u16* src = (k < 128) ? (A1 + (size_t)gr * 128 + k)
                                   : (A2 + (size_t)gr * 128 + (k - 128));
        v = *reinterpret_cast<const uint4*>(src);
      }
      *reinterpret_cast<uint4*>(&As[node][koff]) = v;
    }
#pragma unroll
    for (int i = 0; i < CG / 4; ++i) {
      int c2 = t + i * 256;
      int n = c2 >> 2;
      int koff = (c2 & 3) * 8;
      uint4 v = *reinterpret_cast<const uint4*>(Bt + (size_t)n * 256 + k0 + koff);
      *reinterpret_cast<uint4*>(&Bs[n][koff]) = v;
    }
    __syncthreads();

    bf16x8 a = *reinterpret_cast<const bf16x8*>(&As[arow][kq]);
#pragma unroll
    for (int cg = 0; cg < CG; ++cg) {
      bf16x8 b = *reinterpret_cast<const bf16x8*>(&Bs[cg * 16 + (lane & 15)][kq]);
      acc[cg] = __builtin_amdgcn_mfma_f32_16x16x32_bf16(a, b, acc[cg], 0, 0, 0);
    }
    __syncthreads();
  }

  const int rbase = w * 16 + ((lane >> 4) << 2);
#pragma unroll
  for (int cg = 0; cg < CG; ++cg) {
    int col = cg * 16 + (lane & 15);
    float bia = bias[col];
#pragma unroll
    for (int j = 0; j < 4; ++j) {
      int gr = row0 + rbase + j;
      if (gr < n_rows) {
        float v = acc[cg][j] + bia;
        if (RELU) v = fmaxf(v, 0.f);
        if (OUTBF16) ((u16*)Cout)[(size_t)gr * HO + col] = f2b(v);
        else ((float*)Cout)[(size_t)gr * HO + col] = v;
      }
    }
  }
}

// ---------------------------------------------------------------------------
extern "C" void kernel_launch(void* const* d_in, const int* in_sizes, int n_in,
                              void* d_out, int out_size, void* d_ws, size_t ws_size,
                              hipStream_t stream) {
  const float* x   = (const float*)d_in[0];
  const float* w   = (const float*)d_in[1];
  const int*   ei  = (const int*)d_in[2];   // [2, E]: row0=src, row1=dst
  const float* Wr1 = (const float*)d_in[3];
  const float* br1 = (const float*)d_in[4];
  const float* Wo1 = (const float*)d_in[5];
  const float* Wr2 = (const float*)d_in[6];
  const float* br2 = (const float*)d_in[7];
  const float* Wo2 = (const float*)d_in[8];
  float* out = (float*)d_out;

  // Workspace layout (bytes, all offsets 16B-aligned) — round-9 layout:
  char* ws = (char*)d_ws;
  int*   cntp    = (int*)(ws);                        // N*16 ints      6,400,000
  int*   ovf_cnt = (int*)(ws + 6400000);              // 1 int (+pad)       1,024
  int*   unused0 = (int*)(ws + 6401024);              // (was dhist)        2,048
  int*   unused1 = (int*)(ws + 6403072);              // (was perm)       400,000
  uint4* ovf     = (uint4*)(ws + 6803072);            // 16384 x 16B      262,144
  uint2* slots   = (uint2*)(ws + 7065216);            // N*CAP*8B      25,600,000
  u16*   xb      = (u16*)(ws + 32665216);             // N*128 bf16    25,600,000
  u16*   hb      = (u16*)(ws + 58265216);             // N*128 bf16    25,600,000
  u16*   aggrb   = (u16*)(ws + 83865216);             // N*128 bf16    25,600,000
  u16*   Wt1     = (u16*)(ws + 109465216);            // 128*256 bf16      65,536
  u16*   Wt2     = (u16*)(ws + 109530752);            // 64*256 bf16       32,768
  (void)unused0; (void)unused1;
  // total ~109.6 MB

  const int egrid = (EE + 255) / 256;

  // ---- Prep: bf16 conversions ----
  cvt_x_k<<<NN * DD / 8 / 256, 256, 0, stream>>>(x, xb);
  cvt_w_k<<<(192 * 256 + 255) / 256, 256, 0, stream>>>(Wr1, Wo1, Wr2, Wo2, Wt1, Wt2);

  // ---- Build dst-buckets directly (single atomic pass, partitioned) ----
  hipMemsetAsync(cntp, 0, 6401024, stream);  // zeroes cntp + ovf_cnt
  {
    const int pstep = (NN + NPART - 1) / NPART;
    for (int p = 0; p < NPART; ++p) {
      int lo = p * pstep;
      int hi = min(NN, lo + pstep);
      fill_direct_k<<<egrid, 256, 0, stream>>>(ei, w, cntp, slots, ovf, ovf_cnt, lo, hi, EE);
    }
  }

  const int ggrid = (NN * 16 + 255) / 256;
  const int mgrid = (NN + 63) / 64;
  const int ogrid = (MAX_OVF * 64) / 256;

  // ---- Layer 1 ----
  gather_k<<<ggrid, 256, 0, stream>>>(xb, cntp, slots, aggrb);
  ovf_fix_k<<<ogrid, 256, 0, stream>>>(ovf_cnt, ovf, xb, aggrb);
  gemm_mfma_k<HH, true, true><<<mgrid, 256, 0, stream>>>(aggrb, xb, Wt1, br1, hb, NN);

  // ---- Layer 2 ----
  gather_k<<<ggrid, 256, 0, stream>>>(hb, cntp, slots, aggrb);
  ovf_fix_k<<<ogrid, 256, 0, stream>>>(ovf_cnt, ovf, hb, aggrb);
  gemm_mfma_k<OO, false, false><<<mgrid, 256, 0, stream>>>(aggrb, hb, Wt2, br2, out, NN);
}